// Round 2
// baseline (122.494 us; speedup 1.0000x reference)
//
#include <hip/hip_runtime.h>

// Problem: B=8192, D=256, INNER=64, OUT=256, all fp32 (per reference).
//   inner[b,d] = b2[d] + sum_i relu(x[b,d]*w1[d,i]+b1[d,i])*w2[d,i]
//   g[b,j]     = relu(sum_d inner[b,d]*wo1[j,d] + bo1[j])
//   out[b,o]   = sum_j g[b,j]*wo2[o,j] + bo2[o]

#define B_TOT 8192
#define D_DIM 256
#define I_DIM 64
#define O_DIM 256
#define TB 16   // batch rows per block

// d_ws layout (floats):
//   [0)        w1t [64][256]   w1t[i][d] = w1[d][i]
//   [16384)    b1t [64][256]
//   [32768)    w2t [64][256]
//   [49152)    wo1t[256][64]   wo1t[d][j] = wo1[j][d]
//   [65536)    wo2t[64][256]   wo2t[j][o] = wo2[o][j]
// total 81920 floats = 320 KB

__global__ __launch_bounds__(256)
void kal_prep(const float* __restrict__ w1, const float* __restrict__ b1,
              const float* __restrict__ w2, const float* __restrict__ wo1,
              const float* __restrict__ wo2, float* __restrict__ ws) {
    int idx = blockIdx.x * 256 + threadIdx.x;   // 0 .. 81919
    if (idx >= 5 * 16384) return;
    int seg = idx >> 14;          // which 16384-element segment
    int r   = idx & 16383;
    if (seg < 3) {
        // out[i][d] = in[d][i], in is [256][64]
        int i = r >> 8;           // 0..63
        int d = r & 255;          // 0..255
        const float* src = (seg == 0) ? w1 : ((seg == 1) ? b1 : w2);
        ws[idx] = src[d * I_DIM + i];
    } else if (seg == 3) {
        // wo1t[d][j] = wo1[j][d], wo1 is [64][256]; r = d*64+j
        int d = r >> 6;
        int j = r & 63;
        ws[idx] = wo1[j * D_DIM + d];
    } else {
        // wo2t[j][o] = wo2[o][j], wo2 is [256][64]; r = j*256+o
        int j = r >> 8;
        int o = r & 255;
        ws[idx] = wo2[o * I_DIM + j];
    }
}

__global__ __launch_bounds__(256)
void kal_main(const float* __restrict__ x,  const float* __restrict__ b2,
              const float* __restrict__ bo1, const float* __restrict__ bo2,
              const float* __restrict__ ws, float* __restrict__ out) {
    const float* w1t  = ws;
    const float* b1t  = ws + 16384;
    const float* w2t  = ws + 32768;
    const float* wo1t = ws + 49152;
    const float* wo2t = ws + 65536;

    __shared__ float inner_s[TB][D_DIM];   // 16 KB
    __shared__ float g_s[TB][I_DIM];       // 4 KB

    const int t    = threadIdx.x;
    const int row0 = blockIdx.x * TB;

    // ---------------- Step A: per-feature inner MLPs (thread = d) -----------
    {
        const int d = t;
        float xv[TB];
        #pragma unroll
        for (int b = 0; b < TB; ++b)
            xv[b] = x[(row0 + b) * D_DIM + d];   // coalesced

        float acc[TB];
        const float b2v = b2[d];
        #pragma unroll
        for (int b = 0; b < TB; ++b) acc[b] = b2v;

        for (int i = 0; i < I_DIM; ++i) {
            const float w1v = w1t[i * D_DIM + d];   // coalesced, L1/L2-hot
            const float b1v = b1t[i * D_DIM + d];
            const float w2v = w2t[i * D_DIM + d];
            #pragma unroll
            for (int b = 0; b < TB; ++b) {
                float h = fmaf(xv[b], w1v, b1v);
                h = fmaxf(h, 0.0f);
                acc[b] = fmaf(h, w2v, acc[b]);
            }
        }
        #pragma unroll
        for (int b = 0; b < TB; ++b) inner_s[b][d] = acc[b];
    }
    __syncthreads();

    // ---------------- Step B: inner @ wo1^T + bo1, relu ---------------------
    // thread layout: j = t&63 (64 outputs), grp = t>>6 (4 groups x 4 rows)
    {
        const int j   = t & 63;
        const int grp = t >> 6;
        const float bo1v = bo1[j];
        float gacc[TB / 4];
        #pragma unroll
        for (int r = 0; r < TB / 4; ++r) gacc[r] = bo1v;

        for (int d = 0; d < D_DIM; ++d) {
            const float wv = wo1t[d * I_DIM + j];   // coalesced per 64 lanes
            #pragma unroll
            for (int r = 0; r < TB / 4; ++r) {
                const int b = grp * (TB / 4) + r;
                gacc[r] = fmaf(inner_s[b][d], wv, gacc[r]);  // LDS broadcast
            }
        }
        #pragma unroll
        for (int r = 0; r < TB / 4; ++r)
            g_s[grp * (TB / 4) + r][j] = fmaxf(gacc[r], 0.0f);
    }
    __syncthreads();

    // ---------------- Step C: g @ wo2^T + bo2 (thread = o) ------------------
    {
        const int o = t;
        float oacc[TB];
        const float bo2v = bo2[o];
        #pragma unroll
        for (int b = 0; b < TB; ++b) oacc[b] = bo2v;

        for (int j = 0; j < I_DIM; ++j) {
            const float wv = wo2t[j * O_DIM + o];   // coalesced
            #pragma unroll
            for (int b = 0; b < TB; ++b)
                oacc[b] = fmaf(g_s[b][j], wv, oacc[b]);      // LDS broadcast
        }
        #pragma unroll
        for (int b = 0; b < TB; ++b)
            out[(row0 + b) * O_DIM + o] = oacc[b];           // coalesced
    }
}

extern "C" void kernel_launch(void* const* d_in, const int* in_sizes, int n_in,
                              void* d_out, int out_size, void* d_ws, size_t ws_size,
                              hipStream_t stream) {
    const float* x   = (const float*)d_in[0];
    const float* w1  = (const float*)d_in[1];
    const float* b1  = (const float*)d_in[2];
    const float* w2  = (const float*)d_in[3];
    const float* b2  = (const float*)d_in[4];
    const float* wo1 = (const float*)d_in[5];
    const float* bo1 = (const float*)d_in[6];
    const float* wo2 = (const float*)d_in[7];
    const float* bo2 = (const float*)d_in[8];
    float* out = (float*)d_out;
    float* ws  = (float*)d_ws;

    // transpose weights into workspace (320 KB)
    kal_prep<<<(5 * 16384 + 255) / 256, 256, 0, stream>>>(w1, b1, w2, wo1, wo2, ws);

    // main fused kernel: 512 blocks x 256 threads, 16 batch rows per block
    kal_main<<<B_TOT / TB, 256, 0, stream>>>(x, b2, bo1, bo2, ws, out);
}

// Round 3
// 101.720 us; speedup vs baseline: 1.2042x; 1.2042x over previous
//
#include <hip/hip_runtime.h>

// Problem: B=8192, D=256, INNER=64, OUT=256, all fp32 (per reference).
//   inner[b,d] = b2[d] + sum_i relu(x[b,d]*w1[d,i]+b1[d,i])*w2[d,i]
//   g[b,j]     = relu(sum_d inner[b,d]*wo1[j,d] + bo1[j])
//   out[b,o]   = sum_j g[b,j]*wo2[o,j] + bo2[o]
//
// R2: latency-bound at 20% occupancy (2 waves/SIMD). TB 16->8 doubles grid to
// 1024 blocks (16 waves/CU); B/C loops unrolled x4 with float4 LDS reads.

#define B_TOT 8192
#define D_DIM 256
#define I_DIM 64
#define O_DIM 256
#define TB 8   // batch rows per block

// d_ws layout (floats):
//   [0)        w1t [64][256]   w1t[i][d] = w1[d][i]
//   [16384)    b1t [64][256]
//   [32768)    w2t [64][256]
//   [49152)    wo1t[256][64]   wo1t[d][j] = wo1[j][d]
//   [65536)    wo2t[64][256]   wo2t[j][o] = wo2[o][j]

__global__ __launch_bounds__(256)
void kal_prep(const float* __restrict__ w1, const float* __restrict__ b1,
              const float* __restrict__ w2, const float* __restrict__ wo1,
              const float* __restrict__ wo2, float* __restrict__ ws) {
    int idx = blockIdx.x * 256 + threadIdx.x;   // 0 .. 81919
    if (idx >= 5 * 16384) return;
    int seg = idx >> 14;
    int r   = idx & 16383;
    if (seg < 3) {
        int i = r >> 8;           // 0..63
        int d = r & 255;          // 0..255
        const float* src = (seg == 0) ? w1 : ((seg == 1) ? b1 : w2);
        ws[idx] = src[d * I_DIM + i];
    } else if (seg == 3) {
        int d = r >> 6;
        int j = r & 63;
        ws[idx] = wo1[j * D_DIM + d];
    } else {
        int j = r >> 8;
        int o = r & 255;
        ws[idx] = wo2[o * I_DIM + j];
    }
}

__global__ __launch_bounds__(256)
void kal_main(const float* __restrict__ x,  const float* __restrict__ b2,
              const float* __restrict__ bo1, const float* __restrict__ bo2,
              const float* __restrict__ ws, float* __restrict__ out) {
    const float* w1t  = ws;
    const float* b1t  = ws + 16384;
    const float* w2t  = ws + 32768;
    const float* wo1t = ws + 49152;
    const float* wo2t = ws + 65536;

    __shared__ float inner_s[TB][D_DIM];   // 8 KB
    __shared__ float g_s[TB][I_DIM];       // 2 KB

    const int t    = threadIdx.x;
    const int row0 = blockIdx.x * TB;

    // ---------------- Step A: per-feature inner MLPs (thread = d) -----------
    {
        const int d = t;
        float xv[TB];
        #pragma unroll
        for (int b = 0; b < TB; ++b)
            xv[b] = x[(row0 + b) * D_DIM + d];   // coalesced

        float acc[TB];
        const float b2v = b2[d];
        #pragma unroll
        for (int b = 0; b < TB; ++b) acc[b] = b2v;

        #pragma unroll 4
        for (int i = 0; i < I_DIM; ++i) {
            const float w1v = w1t[i * D_DIM + d];   // coalesced, L2-hot
            const float b1v = b1t[i * D_DIM + d];
            const float w2v = w2t[i * D_DIM + d];
            #pragma unroll
            for (int b = 0; b < TB; ++b) {
                float h = fmaf(xv[b], w1v, b1v);
                h = fmaxf(h, 0.0f);
                acc[b] = fmaf(h, w2v, acc[b]);
            }
        }
        #pragma unroll
        for (int b = 0; b < TB; ++b) inner_s[b][d] = acc[b];
    }
    __syncthreads();

    // ---------------- Step B: inner @ wo1^T + bo1, relu ---------------------
    // thread layout: j = t&63, grp = t>>6 (4 groups x TB/4 rows)
    {
        const int j   = t & 63;
        const int grp = t >> 6;
        const float bo1v = bo1[j];
        float gacc[TB / 4];
        #pragma unroll
        for (int r = 0; r < TB / 4; ++r) gacc[r] = bo1v;

        for (int dd = 0; dd < D_DIM / 4; ++dd) {
            const int d = dd * 4;
            float wv0 = wo1t[(d + 0) * I_DIM + j];
            float wv1 = wo1t[(d + 1) * I_DIM + j];
            float wv2 = wo1t[(d + 2) * I_DIM + j];
            float wv3 = wo1t[(d + 3) * I_DIM + j];
            #pragma unroll
            for (int r = 0; r < TB / 4; ++r) {
                const int b = grp * (TB / 4) + r;
                float4 iv = ((const float4*)&inner_s[b][0])[dd];  // ds_read_b128 bcast
                gacc[r] = fmaf(iv.x, wv0, gacc[r]);
                gacc[r] = fmaf(iv.y, wv1, gacc[r]);
                gacc[r] = fmaf(iv.z, wv2, gacc[r]);
                gacc[r] = fmaf(iv.w, wv3, gacc[r]);
            }
        }
        #pragma unroll
        for (int r = 0; r < TB / 4; ++r)
            g_s[grp * (TB / 4) + r][j] = fmaxf(gacc[r], 0.0f);
    }
    __syncthreads();

    // ---------------- Step C: g @ wo2^T + bo2 (thread = o) ------------------
    {
        const int o = t;
        float oacc[TB];
        const float bo2v = bo2[o];
        #pragma unroll
        for (int b = 0; b < TB; ++b) oacc[b] = bo2v;

        for (int jj = 0; jj < I_DIM / 4; ++jj) {
            const int j = jj * 4;
            float wv0 = wo2t[(j + 0) * O_DIM + o];
            float wv1 = wo2t[(j + 1) * O_DIM + o];
            float wv2 = wo2t[(j + 2) * O_DIM + o];
            float wv3 = wo2t[(j + 3) * O_DIM + o];
            #pragma unroll
            for (int b = 0; b < TB; ++b) {
                float4 gv = ((const float4*)&g_s[b][0])[jj];      // ds_read_b128 bcast
                oacc[b] = fmaf(gv.x, wv0, oacc[b]);
                oacc[b] = fmaf(gv.y, wv1, oacc[b]);
                oacc[b] = fmaf(gv.z, wv2, oacc[b]);
                oacc[b] = fmaf(gv.w, wv3, oacc[b]);
            }
        }
        #pragma unroll
        for (int b = 0; b < TB; ++b)
            out[(row0 + b) * O_DIM + o] = oacc[b];               // coalesced
    }
}

extern "C" void kernel_launch(void* const* d_in, const int* in_sizes, int n_in,
                              void* d_out, int out_size, void* d_ws, size_t ws_size,
                              hipStream_t stream) {
    const float* x   = (const float*)d_in[0];
    const float* w1  = (const float*)d_in[1];
    const float* b1  = (const float*)d_in[2];
    const float* w2  = (const float*)d_in[3];
    const float* b2  = (const float*)d_in[4];
    const float* wo1 = (const float*)d_in[5];
    const float* bo1 = (const float*)d_in[6];
    const float* wo2 = (const float*)d_in[7];
    const float* bo2 = (const float*)d_in[8];
    float* out = (float*)d_out;
    float* ws  = (float*)d_ws;

    kal_prep<<<(5 * 16384 + 255) / 256, 256, 0, stream>>>(w1, b1, w2, wo1, wo2, ws);
    kal_main<<<B_TOT / TB, 256, 0, stream>>>(x, b2, bo1, bo2, ws, out);
}

// Round 4
// 101.586 us; speedup vs baseline: 1.2058x; 1.0013x over previous
//
#include <hip/hip_runtime.h>

// Problem: B=8192, D=256, INNER=64, OUT=256, all fp32 (per reference).
//   inner[b,d] = b2[d] + sum_i relu(x[b,d]*w1[d,i]+b1[d,i])*w2[d,i]
//   g[b,j]     = relu(sum_d inner[b,d]*wo1[j,d] + bo1[j])
//   out[b,o]   = sum_j g[b,j]*wo2[o,j] + bo2[o]
//
// R3: main kernel was VMEM-issue/latency limited (~520 scalar loads/thread vs
// 2560 FMAs, VALUBusy 33%). Prep now packs weights into float4 so every weight
// fetch is one global_load_dwordx4: A (w1,b1,w2) fused, B packs 4 d's, C packs
// 4 j's. Per-thread VMEM instrs ~520 -> ~152.

#define B_TOT 8192
#define D_DIM 256
#define I_DIM 64
#define O_DIM 256
#define TB 8   // batch rows per block

// d_ws layout (float4 units):
//   pa[i*256 + d]  = (w1[d][i], b1[d][i], w2[d][i], 0)      i<64, d<256  -> 16384 float4
//   pb[dd*64 + j]  = (wo1[j][4dd+0..3])                     dd<64, j<64  ->  4096 float4
//   pc[jj*256 + o] = (wo2[o][4jj+0..3])                     jj<16, o<256 ->  4096 float4
// total 24576 float4 = 384 KB

__global__ __launch_bounds__(256)
void kal_prep(const float* __restrict__ w1, const float* __restrict__ b1,
              const float* __restrict__ w2, const float* __restrict__ wo1,
              const float* __restrict__ wo2, float4* __restrict__ ws) {
    int idx = blockIdx.x * 256 + threadIdx.x;   // 0 .. 24575
    if (idx < 16384) {
        int i = idx >> 8;          // 0..63
        int d = idx & 255;         // 0..255
        ws[idx] = make_float4(w1[d * I_DIM + i], b1[d * I_DIM + i],
                              w2[d * I_DIM + i], 0.0f);
    } else if (idx < 16384 + 4096) {
        int r  = idx - 16384;
        int dd = r >> 6;           // 0..63
        int j  = r & 63;           // 0..63
        ws[idx] = ((const float4*)wo1)[j * (D_DIM / 4) + dd];   // wo1[j][4dd..]
    } else if (idx < 16384 + 8192) {
        int r  = idx - (16384 + 4096);
        int jj = r >> 8;           // 0..15
        int o  = r & 255;          // 0..255
        ws[idx] = ((const float4*)wo2)[o * (I_DIM / 4) + jj];   // wo2[o][4jj..]
    }
}

__global__ __launch_bounds__(256)
void kal_main(const float* __restrict__ x,  const float* __restrict__ b2,
              const float* __restrict__ bo1, const float* __restrict__ bo2,
              const float4* __restrict__ ws, float* __restrict__ out) {
    const float4* pa = ws;                 // [64][256]
    const float4* pb = ws + 16384;         // [64][64]
    const float4* pc = ws + 16384 + 4096;  // [16][256]

    __shared__ float inner_s[TB][D_DIM];   // 8 KB
    __shared__ float g_s[TB][I_DIM];       // 2 KB

    const int t    = threadIdx.x;
    const int row0 = blockIdx.x * TB;

    // ---------------- Step A: per-feature inner MLPs (thread = d) -----------
    {
        const int d = t;
        float xv[TB];
        #pragma unroll
        for (int b = 0; b < TB; ++b)
            xv[b] = x[(row0 + b) * D_DIM + d];   // coalesced

        float acc[TB];
        const float b2v = b2[d];
        #pragma unroll
        for (int b = 0; b < TB; ++b) acc[b] = b2v;

        #pragma unroll 8
        for (int i = 0; i < I_DIM; ++i) {
            const float4 w = pa[i * D_DIM + d];   // one dwordx4: (w1,b1,w2,_)
            #pragma unroll
            for (int b = 0; b < TB; ++b) {
                float h = fmaf(xv[b], w.x, w.y);
                h = fmaxf(h, 0.0f);
                acc[b] = fmaf(h, w.z, acc[b]);
            }
        }
        #pragma unroll
        for (int b = 0; b < TB; ++b) inner_s[b][d] = acc[b];
    }
    __syncthreads();

    // ---------------- Step B: inner @ wo1^T + bo1, relu ---------------------
    // thread layout: j = t&63, grp = t>>6 (4 groups x TB/4 rows)
    {
        const int j   = t & 63;
        const int grp = t >> 6;
        const float bo1v = bo1[j];
        float gacc[TB / 4];
        #pragma unroll
        for (int r = 0; r < TB / 4; ++r) gacc[r] = bo1v;

        #pragma unroll 4
        for (int dd = 0; dd < D_DIM / 4; ++dd) {
            const float4 wv = pb[dd * I_DIM + j];   // one dwordx4: 4 d's of wo1
            #pragma unroll
            for (int r = 0; r < TB / 4; ++r) {
                const int b = grp * (TB / 4) + r;
                float4 iv = ((const float4*)&inner_s[b][0])[dd];  // LDS bcast b128
                gacc[r] = fmaf(iv.x, wv.x, gacc[r]);
                gacc[r] = fmaf(iv.y, wv.y, gacc[r]);
                gacc[r] = fmaf(iv.z, wv.z, gacc[r]);
                gacc[r] = fmaf(iv.w, wv.w, gacc[r]);
            }
        }
        #pragma unroll
        for (int r = 0; r < TB / 4; ++r)
            g_s[grp * (TB / 4) + r][j] = fmaxf(gacc[r], 0.0f);
    }
    __syncthreads();

    // ---------------- Step C: g @ wo2^T + bo2 (thread = o) ------------------
    {
        const int o = t;
        float oacc[TB];
        const float bo2v = bo2[o];
        #pragma unroll
        for (int b = 0; b < TB; ++b) oacc[b] = bo2v;

        #pragma unroll 4
        for (int jj = 0; jj < I_DIM / 4; ++jj) {
            const float4 wv = pc[jj * O_DIM + o];   // one dwordx4: 4 j's of wo2
            #pragma unroll
            for (int b = 0; b < TB; ++b) {
                float4 gv = ((const float4*)&g_s[b][0])[jj];      // LDS bcast b128
                oacc[b] = fmaf(gv.x, wv.x, oacc[b]);
                oacc[b] = fmaf(gv.y, wv.y, oacc[b]);
                oacc[b] = fmaf(gv.z, wv.z, oacc[b]);
                oacc[b] = fmaf(gv.w, wv.w, oacc[b]);
            }
        }
        #pragma unroll
        for (int b = 0; b < TB; ++b)
            out[(row0 + b) * O_DIM + o] = oacc[b];               // coalesced
    }
}

extern "C" void kernel_launch(void* const* d_in, const int* in_sizes, int n_in,
                              void* d_out, int out_size, void* d_ws, size_t ws_size,
                              hipStream_t stream) {
    const float* x   = (const float*)d_in[0];
    const float* w1  = (const float*)d_in[1];
    const float* b1  = (const float*)d_in[2];
    const float* w2  = (const float*)d_in[3];
    const float* b2  = (const float*)d_in[4];
    const float* wo1 = (const float*)d_in[5];
    const float* bo1 = (const float*)d_in[6];
    const float* wo2 = (const float*)d_in[7];
    const float* bo2 = (const float*)d_in[8];
    float* out = (float*)d_out;
    float4* ws = (float4*)d_ws;

    kal_prep<<<(24576 + 255) / 256, 256, 0, stream>>>(w1, b1, w2, wo1, wo2, ws);
    kal_main<<<B_TOT / TB, 256, 0, stream>>>(x, b2, bo1, bo2, ws, out);
}

// Round 5
// 90.287 us; speedup vs baseline: 1.3567x; 1.1251x over previous
//
#include <hip/hip_runtime.h>
#include <hip/hip_bf16.h>

// Problem: B=8192, D=256, INNER=64, OUT=256, fp32 in/out.
//   inner[b,d] = b2[d] + sum_i relu(x[b,d]*w1[d,i]+b1[d,i])*w2[d,i]
//   g[b,j]     = relu(sum_d inner[b,d]*wo1[j,d] + bo1[j])
//   out[b,o]   = sum_j g[b,j]*wo2[o,j] + bo2[o]
//
// R5: step A fp32 VALU (relu blocks MFMA); steps B/C via bf16 MFMA
// 16x16x32 (inner/g rounded to bf16, fp32 accum). 512-thr blocks, 16 rows,
// grid 512 (16 waves/CU). Weights pre-packed: A as float4(w1,b1,w2,_),
// wo1/wo2 in MFMA B-fragment order (bf16).

#define B_TOT 8192
#define D_DIM 256
#define I_DIM 64
#define O_DIM 256
#define RB 16          // batch rows per block
#define NT 512         // threads per block

typedef __hip_bfloat16 bf16;
using short8 = __attribute__((ext_vector_type(8))) short;
using f32x4  = __attribute__((ext_vector_type(4))) float;

// d_ws layout:
//   pa  : float4[64*256]      @ byte 0       (256 KB)  (w1[d][i], b1[d][i], w2[d][i], 0) at [i*256+d]
//   pbB : bf16[8*64*32]       @ byte 262144  (32 KB)   pbB[(kc*64+j)*32+kk] = wo1[j][kc*32+kk]
//   pcB : bf16[2*256*32]      @ byte 294912  (32 KB)   pcB[(kc*256+o)*32+kk] = wo2[o][kc*32+kk]

__global__ __launch_bounds__(256)
void kal_prep(const float* __restrict__ w1, const float* __restrict__ b1,
              const float* __restrict__ w2, const float* __restrict__ wo1,
              const float* __restrict__ wo2, float4* __restrict__ ws) {
    int idx = blockIdx.x * 256 + threadIdx.x;   // 0 .. 49151
    if (idx < 16384) {
        int i = idx >> 8;          // 0..63
        int d = idx & 255;         // 0..255
        ws[idx] = make_float4(w1[d * I_DIM + i], b1[d * I_DIM + i],
                              w2[d * I_DIM + i], 0.0f);
    } else if (idx < 32768) {
        int r  = idx - 16384;      // 0..16383 : pbB
        int kc = r >> 11;          // 0..7
        int rem = r & 2047;
        int j  = rem >> 5;         // 0..63
        int kk = rem & 31;         // 0..31
        bf16* pbB = (bf16*)(ws + 16384);
        pbB[r] = __float2bfloat16(wo1[j * D_DIM + kc * 32 + kk]);
    } else if (idx < 49152) {
        int r  = idx - 32768;      // 0..16383 : pcB
        int kc = r >> 13;          // 0..1
        int rem = r & 8191;
        int o  = rem >> 5;         // 0..255
        int kk = rem & 31;         // 0..31
        bf16* pcB = (bf16*)(ws + 16384) + 16384;
        pcB[r] = __float2bfloat16(wo2[o * I_DIM + kc * 32 + kk]);
    }
}

__global__ __launch_bounds__(NT)
void kal_main(const float* __restrict__ x,  const float* __restrict__ b2,
              const float* __restrict__ bo1, const float* __restrict__ bo2,
              const float4* __restrict__ ws, float* __restrict__ out) {
    const float4* pa  = ws;
    const bf16*   pbB = (const bf16*)(ws + 16384);
    const bf16*   pcB = pbB + 16384;

    __shared__ bf16 inner_bf[RB][264];   // +8 pad: b128 frag reads <=2-way bank alias
    __shared__ bf16 g_bf[RB][72];        // +8 pad

    const int t    = threadIdx.x;
    const int row0 = blockIdx.x * RB;

    // ---------------- Step A: per-feature inner MLPs (fp32 VALU) ------------
    {
        const int d    = t & 255;
        const int half = t >> 8;          // waves 0-3: rows 0-7, waves 4-7: rows 8-15
        float xv[8], acc[8];
        const float b2v = b2[d];
        #pragma unroll
        for (int b = 0; b < 8; ++b) {
            xv[b]  = x[(row0 + half * 8 + b) * D_DIM + d];   // coalesced
            acc[b] = b2v;
        }
        #pragma unroll 4
        for (int i = 0; i < I_DIM; ++i) {
            const float4 w = pa[i * D_DIM + d];   // one dwordx4: (w1,b1,w2,_)
            #pragma unroll
            for (int b = 0; b < 8; ++b) {
                float h = fmaf(xv[b], w.x, w.y);
                h = fmaxf(h, 0.0f);
                acc[b] = fmaf(h, w.z, acc[b]);
            }
        }
        #pragma unroll
        for (int b = 0; b < 8; ++b)
            inner_bf[half * 8 + b][d] = __float2bfloat16(acc[b]);
    }
    __syncthreads();

    const int lane = t & 63;
    const int wave = t >> 6;
    const int col  = lane & 15;    // MFMA m/n index
    const int quad = lane >> 4;    // MFMA k-group / row-group

    // ---------------- Step B: [16x256] @ wo1^T -> [16x64], MFMA -------------
    if (wave < 4) {
        const int j0 = wave * 16;            // N-tile
        f32x4 acc = {0.f, 0.f, 0.f, 0.f};
        #pragma unroll
        for (int kc = 0; kc < 8; ++kc) {
            // A-frag: inner[m=col][k=kc*32+quad*8 ..+7], 16B LDS read
            short8 af = *(const short8*)&inner_bf[col][kc * 32 + quad * 8];
            // B-frag: wo1 pre-packed, coalesced dwordx4
            short8 bfr = *(const short8*)&pbB[(kc * 64 + j0 + col) * 32 + quad * 8];
            acc = __builtin_amdgcn_mfma_f32_16x16x32_bf16(af, bfr, acc, 0, 0, 0);
        }
        const float bo1v = bo1[j0 + col];
        #pragma unroll
        for (int r = 0; r < 4; ++r) {
            const int row = quad * 4 + r;    // C/D: row = quad*4+reg, col = lane&15
            g_bf[row][j0 + col] = __float2bfloat16(fmaxf(acc[r] + bo1v, 0.0f));
        }
    }
    __syncthreads();

    // ---------------- Step C: [16x64] @ wo2^T -> [16x256], MFMA -------------
    #pragma unroll
    for (int tile = 0; tile < 2; ++tile) {
        const int o0 = wave * 16 + tile * 128;   // 8 waves x 2 tiles = 16 N-tiles
        f32x4 acc = {0.f, 0.f, 0.f, 0.f};
        #pragma unroll
        for (int kc = 0; kc < 2; ++kc) {
            short8 af = *(const short8*)&g_bf[col][kc * 32 + quad * 8];
            short8 bfr = *(const short8*)&pcB[(kc * 256 + o0 + col) * 32 + quad * 8];
            acc = __builtin_amdgcn_mfma_f32_16x16x32_bf16(af, bfr, acc, 0, 0, 0);
        }
        const float bo2v = bo2[o0 + col];
        #pragma unroll
        for (int r = 0; r < 4; ++r)
            out[(row0 + quad * 4 + r) * O_DIM + o0 + col] = acc[r] + bo2v;
    }
}

extern "C" void kernel_launch(void* const* d_in, const int* in_sizes, int n_in,
                              void* d_out, int out_size, void* d_ws, size_t ws_size,
                              hipStream_t stream) {
    const float* x   = (const float*)d_in[0];
    const float* w1  = (const float*)d_in[1];
    const float* b1  = (const float*)d_in[2];
    const float* w2  = (const float*)d_in[3];
    const float* b2  = (const float*)d_in[4];
    const float* wo1 = (const float*)d_in[5];
    const float* bo1 = (const float*)d_in[6];
    const float* wo2 = (const float*)d_in[7];
    const float* bo2 = (const float*)d_in[8];
    float* out = (float*)d_out;
    float4* ws = (float4*)d_ws;

    kal_prep<<<(49152 + 255) / 256, 256, 0, stream>>>(w1, b1, w2, wo1, wo2, ws);
    kal_main<<<B_TOT / RB, NT, 0, stream>>>(x, b2, bo1, bo2, ws, out);
}